// Round 2
// baseline (775.185 us; speedup 1.0000x reference)
//
#include <hip/hip_runtime.h>
#include <math.h>

#define NN 50000
#define NE 600000
#define ET (NE + NN)        // 650000 edges incl self loops
#define D 128
#define EPSB 1e-5f
#define SLOPE 0.2f

// ---------------- CSR build ----------------
__global__ void hist_kernel(const int* __restrict__ ei, int* __restrict__ deg) {
    int e = blockIdx.x * blockDim.x + threadIdx.x;
    if (e >= ET) return;
    int dst = (e < NE) ? ei[NE + e] : (e - NE);
    atomicAdd(&deg[dst], 1);
}

__global__ __launch_bounds__(1024) void scan_kernel(const int* __restrict__ deg,
                                                    int* __restrict__ offs,
                                                    int* __restrict__ cur) {
    __shared__ int sm[1024];
    __shared__ int carry_sm;
    int t = threadIdx.x;
    if (t == 0) carry_sm = 0;
    __syncthreads();
    for (int base = 0; base < NN; base += 1024) {
        int i = base + t;
        int v = (i < NN) ? deg[i] : 0;
        sm[t] = v;
        __syncthreads();
        for (int d = 1; d < 1024; d <<= 1) {
            int add = (t >= d) ? sm[t - d] : 0;
            __syncthreads();
            sm[t] += add;
            __syncthreads();
        }
        int carry = carry_sm;
        int incl = sm[t];
        if (i < NN) {
            offs[i + 1] = carry + incl;
            cur[i] = carry + incl - v;   // exclusive
        }
        __syncthreads();
        if (t == 1023) carry_sm = carry + incl;
        __syncthreads();
    }
    if (t == 0) offs[0] = 0;
}

__global__ void scatter_kernel(const int* __restrict__ ei, int* __restrict__ cur,
                               int* __restrict__ ssrc) {
    int e = blockIdx.x * blockDim.x + threadIdx.x;
    if (e >= ET) return;
    int src, dst;
    if (e < NE) { src = ei[e]; dst = ei[NE + e]; }
    else        { src = dst = e - NE; }
    int pos = atomicAdd(&cur[dst], 1);
    ssrc[pos] = src;
}

// ---------------- GEMM: H = X @ W  (NN x D) @ (D x D) ----------------
__global__ __launch_bounds__(256) void gemm_kernel(const float* __restrict__ X,
                                                   const float* __restrict__ W,
                                                   float* __restrict__ H) {
    int tx = threadIdx.x;           // 0..31 -> 4 cols each
    int ty = threadIdx.y;           // 0..7  -> row
    int row = blockIdx.x * 8 + ty;
    if (row >= NN) return;
    const float* xr = X + (long)row * D;
    float4 acc = {0.f, 0.f, 0.f, 0.f};
    for (int k = 0; k < D; ++k) {
        float xv = xr[k];
        float4 w = *(const float4*)&W[k * D + tx * 4];
        acc.x += xv * w.x; acc.y += xv * w.y;
        acc.z += xv * w.z; acc.w += xv * w.w;
    }
    *(float4*)&H[(long)row * D + tx * 4] = acc;
}

// ---------------- per-node logits ----------------
template <int H>
__global__ void logits_kernel(const float* __restrict__ Hm,
                              const float* __restrict__ a_src,
                              const float* __restrict__ a_dst,
                              float* __restrict__ es, float* __restrict__ ed) {
    int i = blockIdx.x * blockDim.x + threadIdx.x;
    if (i >= NN * H) return;
    int n = i / H, h = i % H;
    const int CH = D / H;
    const float* hp = Hm + (long)n * D + h * CH;
    const float* as = a_src + h * CH;
    const float* ad = a_dst + h * CH;
    float s = 0.f, d = 0.f;
    for (int c = 0; c < CH; c += 4) {
        float4 hv = *(const float4*)&hp[c];
        float4 av = *(const float4*)&as[c];
        float4 bv = *(const float4*)&ad[c];
        s += hv.x * av.x + hv.y * av.y + hv.z * av.z + hv.w * av.w;
        d += hv.x * bv.x + hv.y * bv.y + hv.z * bv.z + hv.w * bv.w;
    }
    es[i] = s; ed[i] = d;
}

// ---------------- aggregation: one wave per dst node ----------------
// out[dst] = (sum_e w_e * Hm[src_e]) / (sum_e w_e) + bias + resid[dst]
template <int H>
__global__ __launch_bounds__(256) void agg_kernel(const float* __restrict__ Hm,
                                                  const float* __restrict__ es,
                                                  const float* __restrict__ ed,
                                                  const int* __restrict__ offs,
                                                  const int* __restrict__ ssrc,
                                                  const float* __restrict__ bias,
                                                  const float* __restrict__ resid,
                                                  float* __restrict__ out) {
    int wave = threadIdx.x >> 6;
    int lane = threadIdx.x & 63;
    int dst = blockIdx.x * 4 + wave;
    if (dst >= NN) return;
    int h = (H == 1) ? 0 : (lane >> 4);      // feature 2*lane -> head (2*lane)/32
    float edv = ed[dst * H + h];
    int beg = offs[dst], end = offs[dst + 1];
    float2 acc = {0.f, 0.f};
    float dsum = 0.f;
    for (int idx = beg; idx < end; ++idx) {
        int src = ssrc[idx];
        float e = es[src * H + h] + edv;
        e = (e > 0.f) ? e : SLOPE * e;
        float w = __expf(e);
        float2 hv = *(const float2*)&Hm[(long)src * D + lane * 2];
        acc.x += w * hv.x; acc.y += w * hv.y;
        dsum += w;
    }
    float inv = 1.0f / dsum;
    int f = lane * 2;
    float2 r = *(const float2*)&resid[(long)dst * D + f];
    float2 o;
    o.x = acc.x * inv + bias[f]     + r.x;
    o.y = acc.y * inv + bias[f + 1] + r.y;
    *(float2*)&out[(long)dst * D + f] = o;
}

// ---------------- batch-norm stats / finalize / apply ----------------
__global__ __launch_bounds__(128) void stats_kernel(const float* __restrict__ y,
                                                    float* __restrict__ st) {
    int f = threadIdx.x;   // 0..127
    float s = 0.f, q = 0.f;
    for (int r = blockIdx.x; r < NN; r += gridDim.x) {
        float v = y[(long)r * D + f];
        s += v; q += v * v;
    }
    atomicAdd(&st[f], s);
    atomicAdd(&st[D + f], q);
}

__global__ void finalize_kernel(const float* __restrict__ st,
                                const float* __restrict__ gamma,
                                const float* __restrict__ beta,
                                float* __restrict__ scsh) {
    int f = threadIdx.x;
    if (f >= D) return;
    float mean = st[f] * (1.0f / NN);
    float var = st[D + f] * (1.0f / NN) - mean * mean;
    float g = gamma[f] * rsqrtf(var + EPSB);
    scsh[f] = g;
    scsh[D + f] = beta[f] - mean * g;
}

template <bool RELU>
__global__ __launch_bounds__(256) void apply_kernel(const float* __restrict__ y,
                                                    const float* __restrict__ scsh,
                                                    float* __restrict__ out) {
    long i = (long)(blockIdx.x * blockDim.x + threadIdx.x) * 4;
    if (i >= (long)NN * D) return;
    int f = (int)(i & (D - 1));
    float4 v = *(const float4*)&y[i];
    float4 o;
    o.x = v.x * scsh[f]     + scsh[D + f];
    o.y = v.y * scsh[f + 1] + scsh[D + f + 1];
    o.z = v.z * scsh[f + 2] + scsh[D + f + 2];
    o.w = v.w * scsh[f + 3] + scsh[D + f + 3];
    if (RELU) {
        o.x = fmaxf(o.x, 0.f); o.y = fmaxf(o.y, 0.f);
        o.z = fmaxf(o.z, 0.f); o.w = fmaxf(o.w, 0.f);
    }
    *(float4*)&out[i] = o;
}

extern "C" void kernel_launch(void* const* d_in, const int* in_sizes, int n_in,
                              void* d_out, int out_size, void* d_ws, size_t ws_size,
                              hipStream_t stream) {
    const float* x      = (const float*)d_in[0];
    const int*   ei     = (const int*)  d_in[1];
    const float* W1     = (const float*)d_in[2];
    const float* a_src1 = (const float*)d_in[3];
    const float* a_dst1 = (const float*)d_in[4];
    const float* b1     = (const float*)d_in[5];
    const float* W2     = (const float*)d_in[6];
    const float* a_src2 = (const float*)d_in[7];
    const float* a_dst2 = (const float*)d_in[8];
    const float* b2     = (const float*)d_in[9];
    const float* gamma  = (const float*)d_in[10];
    const float* beta   = (const float*)d_in[11];
    float* out = (float*)d_out;

    // workspace layout (floats)
    float* A    = (float*)d_ws;            // h1 / h2 (aliased)  6.4M
    float* B    = A + 6400000;             // y1                 6.4M
    float* Cres = B + 6400000;             // relu(bn(y1))       6.4M
    float* es1  = Cres + 6400000;          // 200000
    float* ed1  = es1 + 200000;            // 200000
    float* es2  = ed1 + 200000;            // 50000
    float* ed2  = es2 + 50000;             // 50000
    float* st1  = ed2 + 50000;             // 256
    float* st2  = st1 + 256;               // 256
    float* ss1  = st2 + 256;               // 256
    float* ss2  = ss1 + 256;               // 256
    int*   deg  = (int*)(ss2 + 256);       // 50000
    int*   offs = deg + NN;                // 50001
    int*   cur  = offs + NN + 1;           // 50000
    int*   ssrc = cur + NN;                // 650000

    hipMemsetAsync(deg, 0, NN * sizeof(int), stream);
    hipMemsetAsync(st1, 0, 512 * sizeof(float), stream);   // st1+st2 contiguous

    // CSR build
    hist_kernel<<<(ET + 255) / 256, 256, 0, stream>>>(ei, deg);
    scan_kernel<<<1, 1024, 0, stream>>>(deg, offs, cur);
    scatter_kernel<<<(ET + 255) / 256, 256, 0, stream>>>(ei, cur, ssrc);

    // ---- layer 1 ----
    gemm_kernel<<<NN / 8, dim3(32, 8), 0, stream>>>(x, W1, A);
    logits_kernel<4><<<(NN * 4 + 255) / 256, 256, 0, stream>>>(A, a_src1, a_dst1, es1, ed1);
    agg_kernel<4><<<(NN + 3) / 4, 256, 0, stream>>>(A, es1, ed1, offs, ssrc, b1, x, B);
    stats_kernel<<<256, 128, 0, stream>>>(B, st1);
    finalize_kernel<<<1, 128, 0, stream>>>(st1, gamma, beta, ss1);
    apply_kernel<true><<<(NN * D / 4 + 255) / 256, 256, 0, stream>>>(B, ss1, Cres);

    // ---- layer 2 ----
    gemm_kernel<<<NN / 8, dim3(32, 8), 0, stream>>>(Cres, W2, A);
    logits_kernel<1><<<(NN + 255) / 256, 256, 0, stream>>>(A, a_src2, a_dst2, es2, ed2);
    agg_kernel<1><<<(NN + 3) / 4, 256, 0, stream>>>(A, es2, ed2, offs, ssrc, b2, Cres, out);
    stats_kernel<<<256, 128, 0, stream>>>(out, st2);
    finalize_kernel<<<1, 128, 0, stream>>>(st2, gamma, beta, ss2);
    apply_kernel<false><<<(NN * D / 4 + 255) / 256, 256, 0, stream>>>(out, ss2, out);
}

// Round 3
// 607.842 us; speedup vs baseline: 1.2753x; 1.2753x over previous
//
#include <hip/hip_runtime.h>
#include <math.h>

#define NN 50000
#define NE 600000
#define ET (NE + NN)        // 650000 edges incl self loops
#define D 128
#define EPSB 1e-5f
#define SLOPE 0.2f
#define XPITCH 136          // LDS row pitch in bf16 elems (128 + 8 pad)

typedef float f32x4 __attribute__((ext_vector_type(4)));
typedef short bf16x8 __attribute__((ext_vector_type(8)));   // 8 bf16 in 4 VGPRs

__device__ inline unsigned short bf16r(float f) {           // f32 -> bf16 RNE
    unsigned int u = __float_as_uint(f);
    unsigned int r = (u + 0x7fff + ((u >> 16) & 1)) >> 16;
    return (unsigned short)r;
}

// ---------------- CSR build ----------------
__global__ void hist_kernel(const int* __restrict__ ei, int* __restrict__ deg) {
    int e = blockIdx.x * blockDim.x + threadIdx.x;
    if (e >= ET) return;
    int dst = (e < NE) ? ei[NE + e] : (e - NE);
    atomicAdd(&deg[dst], 1);
}

// two-phase: serial-per-thread sums + one block scan + serial prefix writeback
__global__ __launch_bounds__(1024) void scan_kernel(const int* __restrict__ deg,
                                                    int* __restrict__ offs,
                                                    int* __restrict__ cur) {
    const int PER = 49;  // 1024*49 = 50176 >= NN
    __shared__ int sm[1024];
    int t = threadIdx.x;
    int base = t * PER;
    int s = 0;
    for (int i = 0; i < PER; ++i) {
        int idx = base + i;
        if (idx < NN) s += deg[idx];
    }
    sm[t] = s;
    __syncthreads();
    for (int d = 1; d < 1024; d <<= 1) {
        int add = (t >= d) ? sm[t - d] : 0;
        __syncthreads();
        sm[t] += add;
        __syncthreads();
    }
    int run = (t == 0) ? 0 : sm[t - 1];     // exclusive prefix of this chunk
    for (int i = 0; i < PER; ++i) {
        int idx = base + i;
        if (idx < NN) {
            int v = deg[idx];
            offs[idx] = run;
            cur[idx] = run;
            run += v;
        }
    }
    if (t == 1023) offs[NN] = run;          // == ET
}

__global__ void scatter_kernel(const int* __restrict__ ei, int* __restrict__ cur,
                               int* __restrict__ ssrc) {
    int e = blockIdx.x * blockDim.x + threadIdx.x;
    if (e >= ET) return;
    int src, dst;
    if (e < NE) { src = ei[e]; dst = ei[NE + e]; }
    else        { src = dst = e - NE; }
    int pos = atomicAdd(&cur[dst], 1);
    ssrc[pos] = src;
}

// ---------------- W -> bf16 transposed:  Wt[n][k] = bf16(W[k][n]) ----------------
__global__ void wconv_kernel(const float* __restrict__ W, unsigned short* __restrict__ Wt) {
    int t = blockIdx.x * blockDim.x + threadIdx.x;
    if (t >= D * D) return;
    int n = t >> 7, k = t & 127;
    Wt[t] = bf16r(W[k * D + n]);
}

// ---------------- MFMA GEMM: H = X(f32) @ W, via bf16 ----------------
// block: 256 thr = 4 waves, 64 rows; wave w -> rows w*16..w*16+15, all 128 cols
__global__ __launch_bounds__(256) void gemm_mfma_kernel(const float* __restrict__ X,
                                                        const unsigned short* __restrict__ Wt,
                                                        float* __restrict__ H, int nrows) {
    __shared__ unsigned short Xl[64 * XPITCH];
    __shared__ unsigned short Wl[128 * XPITCH];
    int t = threadIdx.x;
    int row0 = blockIdx.x * 64;

    // stage Wt (bf16 [128][128]) -> Wl [128][XPITCH], straight copy
    {
        int r = t >> 1, cb = (t & 1) * 64;          // 2 threads/row, 64 elems each
        const uint4* src = (const uint4*)&Wt[r * D + cb];   // uint4 = 8 bf16
        uint4* dst = (uint4*)&Wl[r * XPITCH + cb];
        #pragma unroll
        for (int j = 0; j < 8; ++j) dst[j] = src[j];
    }
    // stage X rows row0..row0+63 (f32 -> bf16) -> Xl
    {
        int r = t >> 2, cb = (t & 3) * 32;          // 4 threads/row, 32 elems each
        int gr = row0 + r; if (gr >= nrows) gr = nrows - 1;
        const float4* src = (const float4*)&X[(long)gr * D + cb];
        #pragma unroll
        for (int j = 0; j < 8; ++j) {
            float4 v = src[j];
            ushort4 p;
            p.x = bf16r(v.x); p.y = bf16r(v.y);
            p.z = bf16r(v.z); p.w = bf16r(v.w);
            *(ushort4*)&Xl[r * XPITCH + cb + j * 4] = p;
        }
    }
    __syncthreads();

    int wv = t >> 6, l = t & 63;
    int lr = l & 15, lg = l >> 4;
    f32x4 acc[8];
    #pragma unroll
    for (int n = 0; n < 8; ++n) acc[n] = (f32x4){0.f, 0.f, 0.f, 0.f};

    #pragma unroll
    for (int kc = 0; kc < 4; ++kc) {
        bf16x8 a = *(const bf16x8*)&Xl[(wv * 16 + lr) * XPITCH + kc * 32 + lg * 8];
        #pragma unroll
        for (int n = 0; n < 8; ++n) {
            bf16x8 b = *(const bf16x8*)&Wl[(n * 16 + lr) * XPITCH + kc * 32 + lg * 8];
            acc[n] = __builtin_amdgcn_mfma_f32_16x16x32_bf16(a, b, acc[n], 0, 0, 0);
        }
    }
    // C/D layout: col = lane&15, row = (lane>>4)*4 + reg
    int growb = row0 + wv * 16 + lg * 4;
    #pragma unroll
    for (int n = 0; n < 8; ++n) {
        #pragma unroll
        for (int j = 0; j < 4; ++j) {
            int gr = growb + j;
            if (gr < nrows) H[(long)gr * D + n * 16 + lr] = acc[n][j];
        }
    }
}

// ---------------- per-node logits ----------------
template <int H>
__global__ void logits_kernel(const float* __restrict__ Hm,
                              const float* __restrict__ a_src,
                              const float* __restrict__ a_dst,
                              float* __restrict__ es, float* __restrict__ ed) {
    int i = blockIdx.x * blockDim.x + threadIdx.x;
    if (i >= NN * H) return;
    int n = i / H, h = i % H;
    const int CH = D / H;
    const float* hp = Hm + (long)n * D + h * CH;
    const float* as = a_src + h * CH;
    const float* ad = a_dst + h * CH;
    float s = 0.f, d = 0.f;
    for (int c = 0; c < CH; c += 4) {
        float4 hv = *(const float4*)&hp[c];
        float4 av = *(const float4*)&as[c];
        float4 bv = *(const float4*)&ad[c];
        s += hv.x * av.x + hv.y * av.y + hv.z * av.z + hv.w * av.w;
        d += hv.x * bv.x + hv.y * bv.y + hv.z * bv.z + hv.w * bv.w;
    }
    es[i] = s; ed[i] = d;
}

// ---------------- aggregation: one wave per dst node ----------------
template <int H>
__global__ __launch_bounds__(256) void agg_kernel(const float* __restrict__ Hm,
                                                  const float* __restrict__ es,
                                                  const float* __restrict__ ed,
                                                  const int* __restrict__ offs,
                                                  const int* __restrict__ ssrc,
                                                  const float* __restrict__ bias,
                                                  const float* __restrict__ resid,
                                                  float* __restrict__ out) {
    int wave = threadIdx.x >> 6;
    int lane = threadIdx.x & 63;
    int dst = blockIdx.x * 4 + wave;
    if (dst >= NN) return;
    int h = (H == 1) ? 0 : (lane >> 4);
    float edv = ed[dst * H + h];
    int beg = offs[dst], end = offs[dst + 1];
    float2 acc = {0.f, 0.f};
    float dsum = 0.f;
    for (int idx = beg; idx < end; ++idx) {
        int src = ssrc[idx];
        float e = es[src * H + h] + edv;
        e = (e > 0.f) ? e : SLOPE * e;
        float w = __expf(e);
        float2 hv = *(const float2*)&Hm[(long)src * D + lane * 2];
        acc.x += w * hv.x; acc.y += w * hv.y;
        dsum += w;
    }
    float inv = 1.0f / dsum;
    int f = lane * 2;
    float2 r = *(const float2*)&resid[(long)dst * D + f];
    float2 o;
    o.x = acc.x * inv + bias[f]     + r.x;
    o.y = acc.y * inv + bias[f + 1] + r.y;
    *(float2*)&out[(long)dst * D + f] = o;
}

// ---------------- batch-norm stats / finalize / apply ----------------
__global__ __launch_bounds__(128) void stats_kernel(const float* __restrict__ y,
                                                    float* __restrict__ st) {
    int f = threadIdx.x;
    float s = 0.f, q = 0.f;
    for (int r = blockIdx.x; r < NN; r += gridDim.x) {
        float v = y[(long)r * D + f];
        s += v; q += v * v;
    }
    atomicAdd(&st[f], s);
    atomicAdd(&st[D + f], q);
}

__global__ void finalize_kernel(const float* __restrict__ st,
                                const float* __restrict__ gamma,
                                const float* __restrict__ beta,
                                float* __restrict__ scsh) {
    int f = threadIdx.x;
    if (f >= D) return;
    float mean = st[f] * (1.0f / NN);
    float var = st[D + f] * (1.0f / NN) - mean * mean;
    float g = gamma[f] * rsqrtf(var + EPSB);
    scsh[f] = g;
    scsh[D + f] = beta[f] - mean * g;
}

template <bool RELU>
__global__ __launch_bounds__(256) void apply_kernel(const float* __restrict__ y,
                                                    const float* __restrict__ scsh,
                                                    float* __restrict__ out) {
    long i = (long)(blockIdx.x * blockDim.x + threadIdx.x) * 4;
    if (i >= (long)NN * D) return;
    int f = (int)(i & (D - 1));
    float4 v = *(const float4*)&y[i];
    float4 o;
    o.x = v.x * scsh[f]     + scsh[D + f];
    o.y = v.y * scsh[f + 1] + scsh[D + f + 1];
    o.z = v.z * scsh[f + 2] + scsh[D + f + 2];
    o.w = v.w * scsh[f + 3] + scsh[D + f + 3];
    if (RELU) {
        o.x = fmaxf(o.x, 0.f); o.y = fmaxf(o.y, 0.f);
        o.z = fmaxf(o.z, 0.f); o.w = fmaxf(o.w, 0.f);
    }
    *(float4*)&out[i] = o;
}

extern "C" void kernel_launch(void* const* d_in, const int* in_sizes, int n_in,
                              void* d_out, int out_size, void* d_ws, size_t ws_size,
                              hipStream_t stream) {
    const float* x      = (const float*)d_in[0];
    const int*   ei     = (const int*)  d_in[1];
    const float* W1     = (const float*)d_in[2];
    const float* a_src1 = (const float*)d_in[3];
    const float* a_dst1 = (const float*)d_in[4];
    const float* b1     = (const float*)d_in[5];
    const float* W2     = (const float*)d_in[6];
    const float* a_src2 = (const float*)d_in[7];
    const float* a_dst2 = (const float*)d_in[8];
    const float* b2     = (const float*)d_in[9];
    const float* gamma  = (const float*)d_in[10];
    const float* beta   = (const float*)d_in[11];
    float* out = (float*)d_out;

    // workspace layout (floats)
    float* A    = (float*)d_ws;            // h1 / h2 (aliased)  6.4M
    float* B    = A + 6400000;             // y1                 6.4M
    float* Cres = B + 6400000;             // relu(bn(y1))       6.4M
    float* es1  = Cres + 6400000;
    float* ed1  = es1 + 200000;
    float* es2  = ed1 + 200000;
    float* ed2  = es2 + 50000;
    float* st1  = ed2 + 50000;
    float* st2  = st1 + 256;
    float* ss1  = st2 + 256;
    float* ss2  = ss1 + 256;
    int*   deg  = (int*)(ss2 + 256);
    int*   offs = deg + NN;
    int*   cur  = offs + NN + 1;
    int*   ssrc = cur + NN;                 // ET ints
    unsigned short* wt1 = (unsigned short*)(ssrc + ET);   // 16384 bf16
    unsigned short* wt2 = wt1 + D * D;

    hipMemsetAsync(deg, 0, NN * sizeof(int), stream);
    hipMemsetAsync(st1, 0, 512 * sizeof(float), stream);

    // weight convert/transpose + CSR build
    wconv_kernel<<<(D * D + 255) / 256, 256, 0, stream>>>(W1, wt1);
    wconv_kernel<<<(D * D + 255) / 256, 256, 0, stream>>>(W2, wt2);
    hist_kernel<<<(ET + 255) / 256, 256, 0, stream>>>(ei, deg);
    scan_kernel<<<1, 1024, 0, stream>>>(deg, offs, cur);
    scatter_kernel<<<(ET + 255) / 256, 256, 0, stream>>>(ei, cur, ssrc);

    const int GG = (NN + 63) / 64;
    // ---- layer 1 ----
    gemm_mfma_kernel<<<GG, 256, 0, stream>>>(x, wt1, A, NN);
    logits_kernel<4><<<(NN * 4 + 255) / 256, 256, 0, stream>>>(A, a_src1, a_dst1, es1, ed1);
    agg_kernel<4><<<(NN + 3) / 4, 256, 0, stream>>>(A, es1, ed1, offs, ssrc, b1, x, B);
    stats_kernel<<<256, 128, 0, stream>>>(B, st1);
    finalize_kernel<<<1, 128, 0, stream>>>(st1, gamma, beta, ss1);
    apply_kernel<true><<<(NN * D / 4 + 255) / 256, 256, 0, stream>>>(B, ss1, Cres);

    // ---- layer 2 ----
    gemm_mfma_kernel<<<GG, 256, 0, stream>>>(Cres, wt2, A, NN);
    logits_kernel<1><<<(NN + 255) / 256, 256, 0, stream>>>(A, a_src2, a_dst2, es2, ed2);
    agg_kernel<1><<<(NN + 3) / 4, 256, 0, stream>>>(A, es2, ed2, offs, ssrc, b2, Cres, out);
    stats_kernel<<<256, 128, 0, stream>>>(out, st2);
    finalize_kernel<<<1, 128, 0, stream>>>(st2, gamma, beta, ss2);
    apply_kernel<false><<<(NN * D / 4 + 255) / 256, 256, 0, stream>>>(out, ss2, out);
}

// Round 4
// 493.006 us; speedup vs baseline: 1.5724x; 1.2329x over previous
//
#include <hip/hip_runtime.h>
#include <math.h>

#define NN 50000
#define NE 600000
#define ET (NE + NN)        // 650000 edges incl self loops
#define D 128
#define EPSB 1e-5f
#define SLOPE 0.2f
#define XPITCH 136          // LDS row pitch in bf16 elems (128 + 8 pad)
#define SCB 196             // scan blocks: 196*256 = 50176 >= NN

typedef float f32x4 __attribute__((ext_vector_type(4)));
typedef short bf16x8 __attribute__((ext_vector_type(8)));   // 8 bf16 in 4 VGPRs

__device__ inline unsigned short bf16r(float f) {           // f32 -> bf16 RNE
    unsigned int u = __float_as_uint(f);
    unsigned int r = (u + 0x7fff + ((u >> 16) & 1)) >> 16;
    return (unsigned short)r;
}

// ---------------- CSR build ----------------
__global__ void hist_kernel(const int* __restrict__ ei, int* __restrict__ deg) {
    int e = blockIdx.x * blockDim.x + threadIdx.x;
    if (e >= ET) return;
    int dst = (e < NE) ? ei[NE + e] : (e - NE);
    atomicAdd(&deg[dst], 1);
}

// multi-block scan, phase A: per-block inclusive scan + block totals
__global__ __launch_bounds__(256) void scan_a_kernel(const int* __restrict__ deg,
                                                     int* __restrict__ tmp,
                                                     int* __restrict__ bsum) {
    __shared__ int sm[256];
    int t = threadIdx.x;
    int idx = blockIdx.x * 256 + t;
    int v = (idx < NN) ? deg[idx] : 0;
    sm[t] = v;
    __syncthreads();
    #pragma unroll
    for (int d = 1; d < 256; d <<= 1) {
        int add = (t >= d) ? sm[t - d] : 0;
        __syncthreads();
        sm[t] += add;
        __syncthreads();
    }
    if (idx < NN) tmp[idx] = sm[t];
    if (t == 255) bsum[blockIdx.x] = sm[255];
}

// phase B: each block redundantly scans bsum[196] in LDS, then applies prefix
__global__ __launch_bounds__(256) void scan_b_kernel(const int* __restrict__ deg,
                                                     const int* __restrict__ tmp,
                                                     const int* __restrict__ bsum,
                                                     int* __restrict__ offs,
                                                     int* __restrict__ cur) {
    __shared__ int sm[256];
    int t = threadIdx.x;
    sm[t] = (t < SCB) ? bsum[t] : 0;
    __syncthreads();
    #pragma unroll
    for (int d = 1; d < 256; d <<= 1) {
        int add = (t >= d) ? sm[t - d] : 0;
        __syncthreads();
        sm[t] += add;
        __syncthreads();
    }
    int bpre = (blockIdx.x == 0) ? 0 : sm[blockIdx.x - 1];
    int idx = blockIdx.x * 256 + t;
    if (idx < NN) {
        int excl = bpre + tmp[idx] - deg[idx];
        offs[idx] = excl;
        cur[idx] = excl;
        if (idx == NN - 1) offs[NN] = bpre + tmp[idx];   // == ET
    }
}

__global__ void scatter_kernel(const int* __restrict__ ei, int* __restrict__ cur,
                               int* __restrict__ ssrc) {
    int e = blockIdx.x * blockDim.x + threadIdx.x;
    if (e >= ET) return;
    int src, dst;
    if (e < NE) { src = ei[e]; dst = ei[NE + e]; }
    else        { src = dst = e - NE; }
    int pos = atomicAdd(&cur[dst], 1);
    ssrc[pos] = src;
}

// ---------------- W -> bf16 transposed:  Wt[n][k] = bf16(W[k][n]) ----------------
__global__ void wconv_kernel(const float* __restrict__ W, unsigned short* __restrict__ Wt) {
    int t = blockIdx.x * blockDim.x + threadIdx.x;
    if (t >= D * D) return;
    int n = t >> 7, k = t & 127;
    Wt[t] = bf16r(W[k * D + n]);
}

// ---------------- MFMA GEMM: H = X(f32) @ W, via bf16 ----------------
__global__ __launch_bounds__(256) void gemm_mfma_kernel(const float* __restrict__ X,
                                                        const unsigned short* __restrict__ Wt,
                                                        float* __restrict__ H, int nrows) {
    __shared__ unsigned short Xl[64 * XPITCH];
    __shared__ unsigned short Wl[128 * XPITCH];
    int t = threadIdx.x;
    int row0 = blockIdx.x * 64;

    {
        int r = t >> 1, cb = (t & 1) * 64;
        const uint4* src = (const uint4*)&Wt[r * D + cb];
        uint4* dst = (uint4*)&Wl[r * XPITCH + cb];
        #pragma unroll
        for (int j = 0; j < 8; ++j) dst[j] = src[j];
    }
    {
        int r = t >> 2, cb = (t & 3) * 32;
        int gr = row0 + r; if (gr >= nrows) gr = nrows - 1;
        const float4* src = (const float4*)&X[(long)gr * D + cb];
        #pragma unroll
        for (int j = 0; j < 8; ++j) {
            float4 v = src[j];
            ushort4 p;
            p.x = bf16r(v.x); p.y = bf16r(v.y);
            p.z = bf16r(v.z); p.w = bf16r(v.w);
            *(ushort4*)&Xl[r * XPITCH + cb + j * 4] = p;
        }
    }
    __syncthreads();

    int wv = t >> 6, l = t & 63;
    int lr = l & 15, lg = l >> 4;
    f32x4 acc[8];
    #pragma unroll
    for (int n = 0; n < 8; ++n) acc[n] = (f32x4){0.f, 0.f, 0.f, 0.f};

    #pragma unroll
    for (int kc = 0; kc < 4; ++kc) {
        bf16x8 a = *(const bf16x8*)&Xl[(wv * 16 + lr) * XPITCH + kc * 32 + lg * 8];
        #pragma unroll
        for (int n = 0; n < 8; ++n) {
            bf16x8 b = *(const bf16x8*)&Wl[(n * 16 + lr) * XPITCH + kc * 32 + lg * 8];
            acc[n] = __builtin_amdgcn_mfma_f32_16x16x32_bf16(a, b, acc[n], 0, 0, 0);
        }
    }
    int growb = row0 + wv * 16 + lg * 4;
    #pragma unroll
    for (int n = 0; n < 8; ++n) {
        #pragma unroll
        for (int j = 0; j < 4; ++j) {
            int gr = growb + j;
            if (gr < nrows) H[(long)gr * D + n * 16 + lr] = acc[n][j];
        }
    }
}

// ---------------- per-node logits ----------------
template <int H>
__global__ void logits_kernel(const float* __restrict__ Hm,
                              const float* __restrict__ a_src,
                              const float* __restrict__ a_dst,
                              float* __restrict__ es, float* __restrict__ ed) {
    int i = blockIdx.x * blockDim.x + threadIdx.x;
    if (i >= NN * H) return;
    int n = i / H, h = i % H;
    const int CH = D / H;
    const float* hp = Hm + (long)n * D + h * CH;
    const float* as = a_src + h * CH;
    const float* ad = a_dst + h * CH;
    float s = 0.f, d = 0.f;
    for (int c = 0; c < CH; c += 4) {
        float4 hv = *(const float4*)&hp[c];
        float4 av = *(const float4*)&as[c];
        float4 bv = *(const float4*)&ad[c];
        s += hv.x * av.x + hv.y * av.y + hv.z * av.z + hv.w * av.w;
        d += hv.x * bv.x + hv.y * bv.y + hv.z * bv.z + hv.w * bv.w;
    }
    es[i] = s; ed[i] = d;
}

// ---------------- aggregation: one wave per dst node ----------------
template <int H>
__global__ __launch_bounds__(256) void agg_kernel(const float* __restrict__ Hm,
                                                  const float* __restrict__ es,
                                                  const float* __restrict__ ed,
                                                  const int* __restrict__ offs,
                                                  const int* __restrict__ ssrc,
                                                  const float* __restrict__ bias,
                                                  const float* __restrict__ resid,
                                                  float* __restrict__ out) {
    int wave = threadIdx.x >> 6;
    int lane = threadIdx.x & 63;
    int dst = blockIdx.x * 4 + wave;
    if (dst >= NN) return;
    int h = (H == 1) ? 0 : (lane >> 4);
    float edv = ed[dst * H + h];
    int beg = offs[dst], end = offs[dst + 1];
    float2 acc = {0.f, 0.f};
    float dsum = 0.f;
    for (int idx = beg; idx < end; ++idx) {
        int src = ssrc[idx];
        float e = es[src * H + h] + edv;
        e = (e > 0.f) ? e : SLOPE * e;
        float w = __expf(e);
        float2 hv = *(const float2*)&Hm[(long)src * D + lane * 2];
        acc.x += w * hv.x; acc.y += w * hv.y;
        dsum += w;
    }
    float inv = 1.0f / dsum;
    int f = lane * 2;
    float2 r = *(const float2*)&resid[(long)dst * D + f];
    float2 o;
    o.x = acc.x * inv + bias[f]     + r.x;
    o.y = acc.y * inv + bias[f + 1] + r.y;
    *(float2*)&out[(long)dst * D + f] = o;
}

// ---------------- batch-norm stats / finalize / apply ----------------
__global__ __launch_bounds__(128) void stats_kernel(const float* __restrict__ y,
                                                    float* __restrict__ st) {
    int f = threadIdx.x;
    float s = 0.f, q = 0.f;
    for (int r = blockIdx.x; r < NN; r += gridDim.x) {
        float v = y[(long)r * D + f];
        s += v; q += v * v;
    }
    atomicAdd(&st[f], s);
    atomicAdd(&st[D + f], q);
}

__global__ void finalize_kernel(const float* __restrict__ st,
                                const float* __restrict__ gamma,
                                const float* __restrict__ beta,
                                float* __restrict__ scsh) {
    int f = threadIdx.x;
    if (f >= D) return;
    float mean = st[f] * (1.0f / NN);
    float var = st[D + f] * (1.0f / NN) - mean * mean;
    float g = gamma[f] * rsqrtf(var + EPSB);
    scsh[f] = g;
    scsh[D + f] = beta[f] - mean * g;
}

template <bool RELU>
__global__ __launch_bounds__(256) void apply_kernel(const float* __restrict__ y,
                                                    const float* __restrict__ scsh,
                                                    float* __restrict__ out) {
    long i = (long)(blockIdx.x * blockDim.x + threadIdx.x) * 4;
    if (i >= (long)NN * D) return;
    int f = (int)(i & (D - 1));
    float4 v = *(const float4*)&y[i];
    float4 o;
    o.x = v.x * scsh[f]     + scsh[D + f];
    o.y = v.y * scsh[f + 1] + scsh[D + f + 1];
    o.z = v.z * scsh[f + 2] + scsh[D + f + 2];
    o.w = v.w * scsh[f + 3] + scsh[D + f + 3];
    if (RELU) {
        o.x = fmaxf(o.x, 0.f); o.y = fmaxf(o.y, 0.f);
        o.z = fmaxf(o.z, 0.f); o.w = fmaxf(o.w, 0.f);
    }
    *(float4*)&out[i] = o;
}

extern "C" void kernel_launch(void* const* d_in, const int* in_sizes, int n_in,
                              void* d_out, int out_size, void* d_ws, size_t ws_size,
                              hipStream_t stream) {
    const float* x      = (const float*)d_in[0];
    const int*   ei     = (const int*)  d_in[1];
    const float* W1     = (const float*)d_in[2];
    const float* a_src1 = (const float*)d_in[3];
    const float* a_dst1 = (const float*)d_in[4];
    const float* b1     = (const float*)d_in[5];
    const float* W2     = (const float*)d_in[6];
    const float* a_src2 = (const float*)d_in[7];
    const float* a_dst2 = (const float*)d_in[8];
    const float* b2     = (const float*)d_in[9];
    const float* gamma  = (const float*)d_in[10];
    const float* beta   = (const float*)d_in[11];
    float* out = (float*)d_out;

    // workspace layout (floats)
    float* A    = (float*)d_ws;            // h1 / h2 (aliased)  6.4M
    float* B    = A + 6400000;             // y1                 6.4M
    float* Cres = B + 6400000;             // relu(bn(y1))       6.4M
    float* es1  = Cres + 6400000;
    float* ed1  = es1 + 200000;
    float* es2  = ed1 + 200000;
    float* ed2  = es2 + 50000;
    float* st1  = ed2 + 50000;
    float* st2  = st1 + 256;
    float* ss1  = st2 + 256;
    float* ss2  = ss1 + 256;
    int*   deg  = (int*)(ss2 + 256);       // NN
    int*   offs = deg + NN;                // NN+1
    int*   cur  = offs + NN + 1;           // NN
    int*   ssrc = cur + NN;                // ET
    int*   tmp  = ssrc + ET;               // NN (scan inclusive)
    int*   bsum = tmp + NN;                // SCB
    unsigned short* wt1 = (unsigned short*)(bsum + SCB + 4);  // 16384 bf16
    unsigned short* wt2 = wt1 + D * D;

    hipMemsetAsync(deg, 0, NN * sizeof(int), stream);
    hipMemsetAsync(st1, 0, 512 * sizeof(float), stream);

    // weight convert/transpose + CSR build
    wconv_kernel<<<(D * D + 255) / 256, 256, 0, stream>>>(W1, wt1);
    wconv_kernel<<<(D * D + 255) / 256, 256, 0, stream>>>(W2, wt2);
    hist_kernel<<<(ET + 255) / 256, 256, 0, stream>>>(ei, deg);
    scan_a_kernel<<<SCB, 256, 0, stream>>>(deg, tmp, bsum);
    scan_b_kernel<<<SCB, 256, 0, stream>>>(deg, tmp, bsum, offs, cur);
    scatter_kernel<<<(ET + 255) / 256, 256, 0, stream>>>(ei, cur, ssrc);

    const int GG = (NN + 63) / 64;
    // ---- layer 1 ----
    gemm_mfma_kernel<<<GG, 256, 0, stream>>>(x, wt1, A, NN);
    logits_kernel<4><<<(NN * 4 + 255) / 256, 256, 0, stream>>>(A, a_src1, a_dst1, es1, ed1);
    agg_kernel<4><<<(NN + 3) / 4, 256, 0, stream>>>(A, es1, ed1, offs, ssrc, b1, x, B);
    stats_kernel<<<256, 128, 0, stream>>>(B, st1);
    finalize_kernel<<<1, 128, 0, stream>>>(st1, gamma, beta, ss1);
    apply_kernel<true><<<(NN * D / 4 + 255) / 256, 256, 0, stream>>>(B, ss1, Cres);

    // ---- layer 2 ----
    gemm_mfma_kernel<<<GG, 256, 0, stream>>>(Cres, wt2, A, NN);
    logits_kernel<1><<<(NN + 255) / 256, 256, 0, stream>>>(A, a_src2, a_dst2, es2, ed2);
    agg_kernel<1><<<(NN + 3) / 4, 256, 0, stream>>>(A, es2, ed2, offs, ssrc, b2, Cres, out);
    stats_kernel<<<256, 128, 0, stream>>>(out, st2);
    finalize_kernel<<<1, 128, 0, stream>>>(st2, gamma, beta, ss2);
    apply_kernel<false><<<(NN * D / 4 + 255) / 256, 256, 0, stream>>>(out, ss2, out);
}

// Round 5
// 375.252 us; speedup vs baseline: 2.0658x; 1.3138x over previous
//
#include <hip/hip_runtime.h>
#include <math.h>

#define NN 50000
#define NE 600000
#define ET (NE + NN)        // 650000 edges incl self loops
#define D 128
#define EPSB 1e-5f
#define SLOPE 0.2f
#define XPITCH 136          // LDS row pitch in bf16 elems (128 + 8 pad)
#define SCB 196             // scan blocks: 196*256 = 50176 >= NN

typedef float f32x4 __attribute__((ext_vector_type(4)));
typedef short bf16x8 __attribute__((ext_vector_type(8)));

__device__ inline unsigned short bf16r(float f) {           // f32 -> bf16 RNE
    unsigned int u = __float_as_uint(f);
    unsigned int r = (u + 0x7fff + ((u >> 16) & 1)) >> 16;
    return (unsigned short)r;
}
__device__ inline float bflo(unsigned int u) { return __uint_as_float(u << 16); }
__device__ inline float bfhi(unsigned int u) { return __uint_as_float(u & 0xffff0000u); }

// ---------------- CSR build ----------------
__global__ void hist_kernel(const int* __restrict__ ei, int* __restrict__ deg) {
    int e = blockIdx.x * blockDim.x + threadIdx.x;
    if (e >= ET) return;
    int dst = (e < NE) ? ei[NE + e] : (e - NE);
    atomicAdd(&deg[dst], 1);
}

__global__ __launch_bounds__(256) void scan_a_kernel(const int* __restrict__ deg,
                                                     int* __restrict__ tmp,
                                                     int* __restrict__ bsum) {
    __shared__ int sm[256];
    int t = threadIdx.x;
    int idx = blockIdx.x * 256 + t;
    int v = (idx < NN) ? deg[idx] : 0;
    sm[t] = v;
    __syncthreads();
    #pragma unroll
    for (int d = 1; d < 256; d <<= 1) {
        int add = (t >= d) ? sm[t - d] : 0;
        __syncthreads();
        sm[t] += add;
        __syncthreads();
    }
    if (idx < NN) tmp[idx] = sm[t];
    if (t == 255) bsum[blockIdx.x] = sm[255];
}

__global__ __launch_bounds__(256) void scan_b_kernel(const int* __restrict__ deg,
                                                     const int* __restrict__ tmp,
                                                     const int* __restrict__ bsum,
                                                     int* __restrict__ offs,
                                                     int* __restrict__ cur) {
    __shared__ int sm[256];
    int t = threadIdx.x;
    sm[t] = (t < SCB) ? bsum[t] : 0;
    __syncthreads();
    #pragma unroll
    for (int d = 1; d < 256; d <<= 1) {
        int add = (t >= d) ? sm[t - d] : 0;
        __syncthreads();
        sm[t] += add;
        __syncthreads();
    }
    int bpre = (blockIdx.x == 0) ? 0 : sm[blockIdx.x - 1];
    int idx = blockIdx.x * 256 + t;
    if (idx < NN) {
        int excl = bpre + tmp[idx] - deg[idx];
        offs[idx] = excl;
        cur[idx] = excl;
        if (idx == NN - 1) offs[NN] = bpre + tmp[idx];   // == ET
    }
}

__global__ void scatter_kernel(const int* __restrict__ ei, int* __restrict__ cur,
                               int* __restrict__ ssrc) {
    int e = blockIdx.x * blockDim.x + threadIdx.x;
    if (e >= ET) return;
    int src, dst;
    if (e < NE) { src = ei[e]; dst = ei[NE + e]; }
    else        { src = dst = e - NE; }
    int pos = atomicAdd(&cur[dst], 1);
    ssrc[pos] = src;
}

// ---------------- both W -> bf16 transposed ----------------
__global__ void wconv_kernel(const float* __restrict__ W1, const float* __restrict__ W2,
                             unsigned short* __restrict__ wt1, unsigned short* __restrict__ wt2) {
    int t = blockIdx.x * blockDim.x + threadIdx.x;
    if (t >= 2 * D * D) return;
    int i = (t < D * D) ? t : t - D * D;
    int n = i >> 7, k = i & 127;
    if (t < D * D) wt1[i] = bf16r(W1[k * D + n]);
    else           wt2[i] = bf16r(W2[k * D + n]);
}

// ---------------- MFMA GEMM: Hb(bf16) = X(f32) @ W ----------------
__global__ __launch_bounds__(256) void gemm_mfma_kernel(const float* __restrict__ X,
                                                        const unsigned short* __restrict__ Wt,
                                                        unsigned short* __restrict__ Hb, int nrows) {
    __shared__ unsigned short Xl[64 * XPITCH];
    __shared__ unsigned short Wl[128 * XPITCH];
    int t = threadIdx.x;
    int row0 = blockIdx.x * 64;

    {
        int r = t >> 1, cb = (t & 1) * 64;
        const uint4* src = (const uint4*)&Wt[r * D + cb];
        uint4* dst = (uint4*)&Wl[r * XPITCH + cb];
        #pragma unroll
        for (int j = 0; j < 8; ++j) dst[j] = src[j];
    }
    {
        int r = t >> 2, cb = (t & 3) * 32;
        int gr = row0 + r; if (gr >= nrows) gr = nrows - 1;
        const float4* src = (const float4*)&X[(long)gr * D + cb];
        #pragma unroll
        for (int j = 0; j < 8; ++j) {
            float4 v = src[j];
            ushort4 p;
            p.x = bf16r(v.x); p.y = bf16r(v.y);
            p.z = bf16r(v.z); p.w = bf16r(v.w);
            *(ushort4*)&Xl[r * XPITCH + cb + j * 4] = p;
        }
    }
    __syncthreads();

    int wv = t >> 6, l = t & 63;
    int lr = l & 15, lg = l >> 4;
    f32x4 acc[8];
    #pragma unroll
    for (int n = 0; n < 8; ++n) acc[n] = (f32x4){0.f, 0.f, 0.f, 0.f};

    #pragma unroll
    for (int kc = 0; kc < 4; ++kc) {
        bf16x8 a = *(const bf16x8*)&Xl[(wv * 16 + lr) * XPITCH + kc * 32 + lg * 8];
        #pragma unroll
        for (int n = 0; n < 8; ++n) {
            bf16x8 b = *(const bf16x8*)&Wl[(n * 16 + lr) * XPITCH + kc * 32 + lg * 8];
            acc[n] = __builtin_amdgcn_mfma_f32_16x16x32_bf16(a, b, acc[n], 0, 0, 0);
        }
    }
    int growb = row0 + wv * 16 + lg * 4;
    #pragma unroll
    for (int n = 0; n < 8; ++n) {
        #pragma unroll
        for (int j = 0; j < 4; ++j) {
            int gr = growb + j;
            if (gr < nrows) Hb[(long)gr * D + n * 16 + lr] = bf16r(acc[n][j]);
        }
    }
}

// ---------------- per-node logits (bf16 H) ----------------
template <int H>
__global__ void logits_kernel(const unsigned short* __restrict__ Hb,
                              const float* __restrict__ a_src,
                              const float* __restrict__ a_dst,
                              float* __restrict__ es, float* __restrict__ ed) {
    int i = blockIdx.x * blockDim.x + threadIdx.x;
    if (i >= NN * H) return;
    int n = i / H, h = i % H;
    const int CH = D / H;
    const unsigned short* hp = Hb + (long)n * D + h * CH;
    const float* as = a_src + h * CH;
    const float* ad = a_dst + h * CH;
    float s = 0.f, d = 0.f;
    for (int c = 0; c < CH; c += 8) {
        uint4 u = *(const uint4*)&hp[c];
        float4 a0 = *(const float4*)&as[c];
        float4 a1 = *(const float4*)&as[c + 4];
        float4 b0 = *(const float4*)&ad[c];
        float4 b1 = *(const float4*)&ad[c + 4];
        float f0 = bflo(u.x), f1 = bfhi(u.x), f2 = bflo(u.y), f3 = bfhi(u.y);
        float f4 = bflo(u.z), f5 = bfhi(u.z), f6 = bflo(u.w), f7 = bfhi(u.w);
        s += f0 * a0.x + f1 * a0.y + f2 * a0.z + f3 * a0.w
           + f4 * a1.x + f5 * a1.y + f6 * a1.z + f7 * a1.w;
        d += f0 * b0.x + f1 * b0.y + f2 * b0.z + f3 * b0.w
           + f4 * b1.x + f5 * b1.y + f6 * b1.z + f7 * b1.w;
    }
    es[i] = s; ed[i] = d;
}

// ---------------- aggregation: one wave per dst, 4-way unrolled gather ----------------
template <int H>
__global__ __launch_bounds__(256) void agg_kernel(const unsigned short* __restrict__ Hb,
                                                  const float* __restrict__ es,
                                                  const float* __restrict__ ed,
                                                  const int* __restrict__ offs,
                                                  const int* __restrict__ ssrc,
                                                  const float* __restrict__ bias,
                                                  const float* __restrict__ resid,
                                                  float* __restrict__ out) {
    int wave = threadIdx.x >> 6;
    int lane = threadIdx.x & 63;
    int dst = blockIdx.x * 4 + wave;
    if (dst >= NN) return;
    int h = (H == 1) ? 0 : (lane >> 4);
    int fo = lane * 2;
    float edv = ed[dst * H + h];
    int beg = offs[dst], end = offs[dst + 1];
    float2 a0 = {0.f,0.f}, a1 = {0.f,0.f}, a2 = {0.f,0.f}, a3 = {0.f,0.f};
    float d0 = 0.f, d1 = 0.f, d2 = 0.f, d3 = 0.f;
    int idx = beg;
    for (; idx + 3 < end; idx += 4) {
        int s0 = ssrc[idx], s1 = ssrc[idx+1], s2 = ssrc[idx+2], s3 = ssrc[idx+3];
        unsigned int u0 = *(const unsigned int*)&Hb[(long)s0 * D + fo];
        unsigned int u1 = *(const unsigned int*)&Hb[(long)s1 * D + fo];
        unsigned int u2 = *(const unsigned int*)&Hb[(long)s2 * D + fo];
        unsigned int u3 = *(const unsigned int*)&Hb[(long)s3 * D + fo];
        float e0 = es[s0*H+h] + edv; e0 = (e0 > 0.f) ? e0 : SLOPE*e0; float w0 = __expf(e0);
        float e1 = es[s1*H+h] + edv; e1 = (e1 > 0.f) ? e1 : SLOPE*e1; float w1 = __expf(e1);
        float e2 = es[s2*H+h] + edv; e2 = (e2 > 0.f) ? e2 : SLOPE*e2; float w2 = __expf(e2);
        float e3 = es[s3*H+h] + edv; e3 = (e3 > 0.f) ? e3 : SLOPE*e3; float w3 = __expf(e3);
        a0.x += w0 * bflo(u0); a0.y += w0 * bfhi(u0); d0 += w0;
        a1.x += w1 * bflo(u1); a1.y += w1 * bfhi(u1); d1 += w1;
        a2.x += w2 * bflo(u2); a2.y += w2 * bfhi(u2); d2 += w2;
        a3.x += w3 * bflo(u3); a3.y += w3 * bfhi(u3); d3 += w3;
    }
    for (; idx < end; ++idx) {
        int s0 = ssrc[idx];
        unsigned int u0 = *(const unsigned int*)&Hb[(long)s0 * D + fo];
        float e0 = es[s0*H+h] + edv; e0 = (e0 > 0.f) ? e0 : SLOPE*e0; float w0 = __expf(e0);
        a0.x += w0 * bflo(u0); a0.y += w0 * bfhi(u0); d0 += w0;
    }
    float dsum = (d0 + d1) + (d2 + d3);
    float accx = (a0.x + a1.x) + (a2.x + a3.x);
    float accy = (a0.y + a1.y) + (a2.y + a3.y);
    float inv = 1.0f / dsum;
    float2 r = *(const float2*)&resid[(long)dst * D + fo];
    float2 o;
    o.x = accx * inv + bias[fo]     + r.x;
    o.y = accy * inv + bias[fo + 1] + r.y;
    *(float2*)&out[(long)dst * D + fo] = o;
}

// ---------------- batch-norm stats + fused finalize/apply ----------------
__global__ __launch_bounds__(128) void stats_kernel(const float* __restrict__ y,
                                                    float* __restrict__ st) {
    int f = threadIdx.x;
    float s = 0.f, q = 0.f;
    for (int r = blockIdx.x; r < NN; r += gridDim.x) {
        float v = y[(long)r * D + f];
        s += v; q += v * v;
    }
    atomicAdd(&st[f], s);
    atomicAdd(&st[D + f], q);
}

template <bool RELU>
__global__ __launch_bounds__(256) void apply_kernel(const float* __restrict__ y,
                                                    const float* __restrict__ st,
                                                    const float* __restrict__ gamma,
                                                    const float* __restrict__ beta,
                                                    float* __restrict__ out) {
    long i = (long)(blockIdx.x * blockDim.x + threadIdx.x) * 4;
    if (i >= (long)NN * D) return;
    int f = (int)(i & (D - 1));
    const float invn = 1.0f / NN;
    float4 sv = *(const float4*)&st[f];
    float4 qv = *(const float4*)&st[D + f];
    float4 gv = *(const float4*)&gamma[f];
    float4 bv = *(const float4*)&beta[f];
    float4 v = *(const float4*)&y[i];
    float4 o;
    float m, vr, g;
    m = sv.x * invn; vr = qv.x * invn - m * m; g = gv.x * rsqrtf(vr + EPSB);
    o.x = (v.x - m) * g + bv.x;
    m = sv.y * invn; vr = qv.y * invn - m * m; g = gv.y * rsqrtf(vr + EPSB);
    o.y = (v.y - m) * g + bv.y;
    m = sv.z * invn; vr = qv.z * invn - m * m; g = gv.z * rsqrtf(vr + EPSB);
    o.z = (v.z - m) * g + bv.z;
    m = sv.w * invn; vr = qv.w * invn - m * m; g = gv.w * rsqrtf(vr + EPSB);
    o.w = (v.w - m) * g + bv.w;
    if (RELU) {
        o.x = fmaxf(o.x, 0.f); o.y = fmaxf(o.y, 0.f);
        o.z = fmaxf(o.z, 0.f); o.w = fmaxf(o.w, 0.f);
    }
    *(float4*)&out[i] = o;
}

extern "C" void kernel_launch(void* const* d_in, const int* in_sizes, int n_in,
                              void* d_out, int out_size, void* d_ws, size_t ws_size,
                              hipStream_t stream) {
    const float* x      = (const float*)d_in[0];
    const int*   ei     = (const int*)  d_in[1];
    const float* W1     = (const float*)d_in[2];
    const float* a_src1 = (const float*)d_in[3];
    const float* a_dst1 = (const float*)d_in[4];
    const float* b1     = (const float*)d_in[5];
    const float* W2     = (const float*)d_in[6];
    const float* a_src2 = (const float*)d_in[7];
    const float* a_dst2 = (const float*)d_in[8];
    const float* b2     = (const float*)d_in[9];
    const float* gamma  = (const float*)d_in[10];
    const float* beta   = (const float*)d_in[11];
    float* out = (float*)d_out;

    // workspace layout
    unsigned short* Hb = (unsigned short*)d_ws;          // 6.4M bf16 (12.8 MB)
    float* B    = (float*)d_ws + 3200000;                // y1   6.4M floats
    float* Cres = B + 6400000;                           // relu(bn(y1))
    float* es1  = Cres + 6400000;                        // 200000
    float* ed1  = es1 + 200000;
    float* es2  = ed1 + 200000;                          // 50000
    float* ed2  = es2 + 50000;
    float* st1  = ed2 + 50000;                           // 256
    float* st2  = st1 + 256;
    int*   deg  = (int*)(st2 + 256);                     // NN
    int*   offs = deg + NN;                              // NN+1
    int*   cur  = offs + NN + 1;                         // NN
    int*   ssrc = cur + NN;                              // ET
    int*   tmp  = ssrc + ET;                             // NN
    int*   bsum = tmp + NN;                              // SCB
    unsigned short* wt1 = (unsigned short*)(bsum + SCB + 4);
    unsigned short* wt2 = wt1 + D * D;

    hipMemsetAsync(deg, 0, NN * sizeof(int), stream);
    hipMemsetAsync(st1, 0, 512 * sizeof(float), stream);

    wconv_kernel<<<(2 * D * D + 255) / 256, 256, 0, stream>>>(W1, W2, wt1, wt2);
    hist_kernel<<<(ET + 255) / 256, 256, 0, stream>>>(ei, deg);
    scan_a_kernel<<<SCB, 256, 0, stream>>>(deg, tmp, bsum);
    scan_b_kernel<<<SCB, 256, 0, stream>>>(deg, tmp, bsum, offs, cur);
    scatter_kernel<<<(ET + 255) / 256, 256, 0, stream>>>(ei, cur, ssrc);

    const int GG = (NN + 63) / 64;
    // ---- layer 1 ----
    gemm_mfma_kernel<<<GG, 256, 0, stream>>>(x, wt1, Hb, NN);
    logits_kernel<4><<<(NN * 4 + 255) / 256, 256, 0, stream>>>(Hb, a_src1, a_dst1, es1, ed1);
    agg_kernel<4><<<(NN + 3) / 4, 256, 0, stream>>>(Hb, es1, ed1, offs, ssrc, b1, x, B);
    stats_kernel<<<1024, 128, 0, stream>>>(B, st1);
    apply_kernel<true><<<(NN * D / 4 + 255) / 256, 256, 0, stream>>>(B, st1, gamma, beta, Cres);

    // ---- layer 2 ----
    gemm_mfma_kernel<<<GG, 256, 0, stream>>>(Cres, wt2, Hb, NN);
    logits_kernel<1><<<(NN + 255) / 256, 256, 0, stream>>>(Hb, a_src2, a_dst2, es2, ed2);
    agg_kernel<1><<<(NN + 3) / 4, 256, 0, stream>>>(Hb, es2, ed2, offs, ssrc, b2, Cres, out);
    stats_kernel<<<1024, 128, 0, stream>>>(out, st2);
    apply_kernel<false><<<(NN * D / 4 + 255) / 256, 256, 0, stream>>>(out, st2, gamma, beta, out);
}